// Round 2
// baseline (205.454 us; speedup 1.0000x reference)
//
#include <hip/hip_runtime.h>
#include <stdint.h>

#define N_NODES 50000
#define N_EDGES 800000
#define IN_F 128
#define HID_F 128
#define OUT_F 128
#define CAT_F 256
#define N_STRIPS 3125  // 50000 / 16 rows per wave-strip

#define NB 256            // edge partition blocks
#define CHUNK 3136        // edges per partition (int4-aligned; 256*3136 >= 800000)
#define NBUCK 3125        // 16-node buckets (50000/16 exact)
#define BCAP 384          // per-bucket record capacity (mean 256, sigma 16, +8 sigma)

typedef __bf16 bf16x8 __attribute__((ext_vector_type(8)));
typedef float f32x4 __attribute__((ext_vector_type(4)));

__device__ __forceinline__ uint32_t f2b(float f) {
  uint32_t u = __float_as_uint(f);
  return (u + 0x7fffu + ((u >> 16) & 1u)) >> 16;  // RNE
}

// ---- K1: fused  [0,NB): per-partition bucket histogram | [NB,..): h/Qw/Ww -> bf16
__global__ void __launch_bounds__(256) prep_hist_kernel(
    const int* __restrict__ dst, int* __restrict__ G, const float* __restrict__ h,
    const float* __restrict__ Qw, const float* __restrict__ Ww, uint16_t* __restrict__ hB,
    uint16_t* __restrict__ QwB, uint16_t* __restrict__ WwB) {
  if (blockIdx.x < NB) {
    __shared__ int hist[NBUCK];  // 12.5 KB
    for (int k = threadIdx.x; k < NBUCK; k += 256) hist[k] = 0;
    __syncthreads();
    int b = blockIdx.x;
    int base = b * CHUNK;
    int end = (base + CHUNK < N_EDGES) ? (base + CHUNK) : N_EDGES;
    for (int i4 = base / 4 + threadIdx.x; i4 * 4 < end; i4 += 256) {
      int4 d4 = ((const int4*)dst)[i4];  // CHUNK,N_EDGES divisible by 4
      atomicAdd(&hist[d4.x >> 4], 1);
      atomicAdd(&hist[d4.y >> 4], 1);
      atomicAdd(&hist[d4.z >> 4], 1);
      atomicAdd(&hist[d4.w >> 4], 1);
    }
    __syncthreads();
    for (int k = threadIdx.x; k < NBUCK; k += 256) G[k * NB + b] = hist[k];
  } else {
    const int TOT4 = (N_NODES * IN_F + HID_F * IN_F + OUT_F * CAT_F) / 4;  // 1612288
    int i4 = (blockIdx.x - NB) * 256 + threadIdx.x;
    if (i4 >= TOT4) return;
    int base = i4 * 4;
    const float* src;
    uint16_t* dstp;
    int off;
    if (base < N_NODES * IN_F) {
      src = h; dstp = hB; off = base;
    } else if (base < N_NODES * IN_F + HID_F * IN_F) {
      src = Qw; dstp = QwB; off = base - N_NODES * IN_F;
    } else {
      src = Ww; dstp = WwB; off = base - N_NODES * IN_F - HID_F * IN_F;
    }
    float4 v = *(const float4*)(src + off);
    ushort4 o;
    o.x = (uint16_t)f2b(v.x); o.y = (uint16_t)f2b(v.y);
    o.z = (uint16_t)f2b(v.z); o.w = (uint16_t)f2b(v.w);
    *(ushort4*)(dstp + off) = o;
  }
}

// ---- K2a: per-bucket exclusive scan over its NB=256 partition counts (one wave/bucket)
__global__ void __launch_bounds__(256) bucket_scan_kernel(const int* __restrict__ G,
                                                          int* __restrict__ Gs,
                                                          int* __restrict__ Btot) {
  int w = (blockIdx.x * 256 + (int)threadIdx.x) >> 6;  // bucket id
  if (w >= NBUCK) return;
  int lane = threadIdx.x & 63;
  int4 v = *(const int4*)(G + (size_t)w * NB + lane * 4);
  int s = v.x + v.y + v.z + v.w;
  int inc = s;
#pragma unroll
  for (int d = 1; d < 64; d <<= 1) {
    int x = __shfl_up(inc, d, 64);
    if (lane >= d) inc += x;
  }
  int exc = inc - s;
  int4 o;
  o.x = exc;
  o.y = exc + v.x;
  o.z = exc + v.x + v.y;
  o.w = exc + v.x + v.y + v.z;
  *(int4*)(Gs + (size_t)w * NB + lane * 4) = o;
  if (lane == 63) Btot[w] = inc;
}

// ---- K2b: single-wave exclusive scan of NBUCK bucket totals -> Bbase[NBUCK+1]
__global__ void base_scan_kernel(const int* __restrict__ Btot, int* __restrict__ Bbase) {
  int lane = threadIdx.x;  // 64 threads, 49 elems each (3136 >= 3126)
  int c[49], loc[49];
  int s = 0;
#pragma unroll
  for (int j = 0; j < 49; ++j) {
    int i = lane * 49 + j;
    c[j] = (i < NBUCK) ? Btot[i] : 0;
    loc[j] = s;
    s += c[j];
  }
  int inc = s;
#pragma unroll
  for (int d = 1; d < 64; d <<= 1) {
    int x = __shfl_up(inc, d, 64);
    if (lane >= d) inc += x;
  }
  int exc = inc - s;
#pragma unroll
  for (int j = 0; j < 49; ++j) {
    int i = lane * 49 + j;
    if (i <= NBUCK) Bbase[i] = exc + loc[j];
  }
}

// ---- GEMM1 body: hq = bf16(hB @ Qw^T + Qb), one wave per 16-row strip
__device__ __forceinline__ void gemm1_body(int gb, const uint16_t* __restrict__ hB,
                                           const uint16_t* __restrict__ QwB,
                                           const float* __restrict__ Qb,
                                           uint16_t* __restrict__ hqB) {
  int wave = (gb * 256 + (int)threadIdx.x) >> 6;
  if (wave >= N_STRIPS) return;
  int lane = threadIdx.x & 63;
  int r = lane & 15, qd = lane >> 4;
  int row0 = wave * 16;
  f32x4 acc[8];
#pragma unroll
  for (int t = 0; t < 8; ++t) acc[t] = (f32x4){0.f, 0.f, 0.f, 0.f};
  const uint16_t* aRow = hB + (size_t)(row0 + r) * IN_F + qd * 8;
#pragma unroll
  for (int kt = 0; kt < 4; ++kt) {
    bf16x8 a = *(const bf16x8*)(aRow + kt * 32);
#pragma unroll
    for (int t = 0; t < 8; ++t) {
      bf16x8 b = *(const bf16x8*)(QwB + (t * 16 + r) * IN_F + kt * 32 + qd * 8);
      acc[t] = __builtin_amdgcn_mfma_f32_16x16x32_bf16(a, b, acc[t], 0, 0, 0);
    }
  }
#pragma unroll
  for (int t = 0; t < 8; ++t) {
    float qb = Qb[t * 16 + r];
#pragma unroll
    for (int rr = 0; rr < 4; ++rr) {
      int m = row0 + qd * 4 + rr;
      hqB[(size_t)m * HID_F + t * 16 + r] = (uint16_t)f2b(acc[t][rr] + qb);
    }
  }
}

// ---- K3: fused  [0,NB): LDS-cursor scatter (int4 edge loads) | [NB,..): gemm1
__global__ void __launch_bounds__(256) scatter_gemm1_kernel(
    const int* __restrict__ dst, const int* __restrict__ src, const float* __restrict__ ppr,
    const int* __restrict__ Gs, const int* __restrict__ Bbase, int2* __restrict__ rec,
    const uint16_t* __restrict__ hB, const uint16_t* __restrict__ QwB,
    const float* __restrict__ Qb, uint16_t* __restrict__ hqB) {
  if (blockIdx.x < NB) {
    __shared__ int cursor[NBUCK];  // 12.5 KB
    int b = blockIdx.x;
    for (int k = threadIdx.x; k < NBUCK; k += 256)
      cursor[k] = Bbase[k] + Gs[(size_t)k * NB + b];
    __syncthreads();
    int base = b * CHUNK;
    int end = (base + CHUNK < N_EDGES) ? (base + CHUNK) : N_EDGES;
    for (int i4 = base / 4 + threadIdx.x; i4 * 4 < end; i4 += 256) {
      int4 d4 = ((const int4*)dst)[i4];
      int4 s4 = ((const int4*)src)[i4];
      float4 w4 = ((const float4*)ppr)[i4];
      int p;
      p = atomicAdd(&cursor[d4.x >> 4], 1);
      rec[p] = make_int2(s4.x | ((d4.x & 15) << 20), __float_as_int(w4.x));
      p = atomicAdd(&cursor[d4.y >> 4], 1);
      rec[p] = make_int2(s4.y | ((d4.y & 15) << 20), __float_as_int(w4.y));
      p = atomicAdd(&cursor[d4.z >> 4], 1);
      rec[p] = make_int2(s4.z | ((d4.z & 15) << 20), __float_as_int(w4.z));
      p = atomicAdd(&cursor[d4.w >> 4], 1);
      rec[p] = make_int2(s4.w | ((d4.w & 15) << 20), __float_as_int(w4.w));
    }
  } else {
    gemm1_body(blockIdx.x - NB, hB, QwB, Qb, hqB);
  }
}

// ---- K4: fused aggregation + GEMM2. Block g (256 thr, 4 waves) owns 16 nodes.
// R2 restructure: TLP instead of ILP. R1 showed the compiler serializes deep
// register batches (VGPR fell to 48 < the 57 needed for 8 loads in flight), so
// raise resident waves instead: 16-node buckets -> grid 3125 (12.2 blocks/CU),
// LDS 7.7 KB, __launch_bounds__(256,8) caps VGPR at 64 -> 8 blocks * 4 waves =
// 32 waves/CU (wave-slot limit) with refill, vs 24 grid-limited before.
// P1: records -> regs + LDS histogram. P2: 16-counter scan. P3: reg -> LDS
// node-sorted scatter. P4: 16 subs x 1 node, 4-deep edge batches. P5: gemm2
// 16-row strip on wave 0 only.
__global__ void __launch_bounds__(256, 8) agg_gemm2_kernel(
    const uint16_t* __restrict__ hqB, const int2* __restrict__ rec,
    const int* __restrict__ Bbase, const uint16_t* __restrict__ hB,
    const uint16_t* __restrict__ WwB, const float* __restrict__ Wb,
    float* __restrict__ out) {
  __shared__ int2 srec[BCAP];     // 3.0 KB
  __shared__ uint4 hagg[16][17];  // 4.4 KB (pad 16->17 breaks stride conflicts)
  __shared__ int hist[16];
  __shared__ int noff[17];
  __shared__ int cur[16];
  int g = blockIdx.x;
  int t = threadIdx.x;
  if (t < 16) hist[t] = 0;
  __syncthreads();

  int rbeg = Bbase[g];
  int len = Bbase[g + 1] - rbeg;
  len = (len < BCAP) ? len : BCAP;

  // P1: load to registers + histogram (2*256 >= BCAP)
  int2 rc[2];
#pragma unroll
  for (int k = 0; k < 2; ++k) {
    int i = t + k * 256;
    if (i < len) {
      rc[k] = rec[rbeg + i];
      atomicAdd(&hist[rc[k].x >> 20], 1);
    }
  }
  __syncthreads();

  // P2: exclusive scan of 16 counters (lanes 0..15 of wave 0)
  if (t < 16) {
    int v = hist[t];
    int inc = v;
#pragma unroll
    for (int d = 1; d < 16; d <<= 1) {
      int x = __shfl_up(inc, d, 64);
      if (t >= d) inc += x;
    }
    noff[t] = inc - v;
    cur[t] = inc - v;
    if (t == 15) noff[16] = inc;
  }
  __syncthreads();

  // P3: scatter registers -> node-sorted LDS
#pragma unroll
  for (int k = 0; k < 2; ++k) {
    int i = t + k * 256;
    if (i < len) {
      int p = atomicAdd(&cur[rc[k].x >> 20], 1);
      srec[p] = rc[k];
    }
  }
  __syncthreads();

  // P4: sub-as-node aggregation. 16 subs of 16 lanes; each sub owns 1 node.
  {
    int gs = t >> 4, c = t & 15;
    const uint4* hq4 = (const uint4*)hqB;
    int nl = gs;  // node = g*16 + nl; 3125*16 = 50000 exactly, always valid
    int nbeg = noff[nl], nend = noff[nl + 1];
    float a[8];
#pragma unroll
    for (int j = 0; j < 8; ++j) a[j] = 0.f;
    float ws = 0.f;
    for (int e0 = nbeg; e0 < nend; e0 += 4) {
      int last = nend - 1;
      int2 rr[4];
#pragma unroll
      for (int j = 0; j < 4; ++j) {
        int i = e0 + j;
        rr[j] = srec[(i < last) ? i : last];  // same addr across 16 c-lanes: broadcast
      }
      uint4 u[4];
#pragma unroll
      for (int j = 0; j < 4; ++j) u[j] = hq4[(size_t)(rr[j].x & 0xFFFFF) * 16 + c];
#pragma unroll
      for (int j = 0; j < 4; ++j) {
        float w = (e0 + j < nend) ? __int_as_float(rr[j].y) : 0.f;
        ws += w;
        uint32_t x;
        x = u[j].x;
        a[0] += w * __uint_as_float(x << 16);
        a[1] += w * __uint_as_float(x & 0xffff0000u);
        x = u[j].y;
        a[2] += w * __uint_as_float(x << 16);
        a[3] += w * __uint_as_float(x & 0xffff0000u);
        x = u[j].z;
        a[4] += w * __uint_as_float(x << 16);
        a[5] += w * __uint_as_float(x & 0xffff0000u);
        x = u[j].w;
        a[6] += w * __uint_as_float(x << 16);
        a[7] += w * __uint_as_float(x & 0xffff0000u);
      }
    }
    float dnm = (ws == 0.f) ? 1.f : ws;  // safediv
    float inv = 1.f / dnm;
    uint4 o;
    o.x = f2b(a[0] * inv) | (f2b(a[1] * inv) << 16);
    o.y = f2b(a[2] * inv) | (f2b(a[3] * inv) << 16);
    o.z = f2b(a[4] * inv) | (f2b(a[5] * inv) << 16);
    o.w = f2b(a[6] * inv) | (f2b(a[7] * inv) << 16);
    hagg[nl][c] = o;
  }
  __syncthreads();

  // P5: gemm2 on wave 0 (16-row strip); waves 1-3 retire
  int lane = t & 63, wv = t >> 6;
  if (wv != 0) return;
  int row0 = g * 16;
  int r = lane & 15, qd = lane >> 4;
  f32x4 acc[8];
#pragma unroll
  for (int tt = 0; tt < 8; ++tt) acc[tt] = (f32x4){0.f, 0.f, 0.f, 0.f};
  const uint16_t* aRow = hB + (size_t)(row0 + r) * IN_F + qd * 8;
#pragma unroll
  for (int kt = 0; kt < 8; ++kt) {
    bf16x8 av;
    if (kt < 4) {
      av = *(const bf16x8*)(aRow + kt * 32);
    } else {
      av = *(const bf16x8*)&hagg[r][(kt - 4) * 4 + qd];
    }
#pragma unroll
    for (int tt = 0; tt < 8; ++tt) {
      bf16x8 b = *(const bf16x8*)(WwB + (tt * 16 + r) * CAT_F + kt * 32 + qd * 8);
      acc[tt] = __builtin_amdgcn_mfma_f32_16x16x32_bf16(av, b, acc[tt], 0, 0, 0);
    }
  }
  float lv[8][4];
  float ss[4] = {0.f, 0.f, 0.f, 0.f};
#pragma unroll
  for (int tt = 0; tt < 8; ++tt) {
    float wb = Wb[tt * 16 + r];
#pragma unroll
    for (int rr2 = 0; rr2 < 4; ++rr2) {
      float v = acc[tt][rr2] + wb;
      v = (v >= 0.f) ? v : 0.01f * v;
      lv[tt][rr2] = v;
      ss[rr2] += v * v;
    }
  }
#pragma unroll
  for (int rr2 = 0; rr2 < 4; ++rr2) {
    float s = ss[rr2];
    s += __shfl_xor(s, 1);
    s += __shfl_xor(s, 2);
    s += __shfl_xor(s, 4);
    s += __shfl_xor(s, 8);
    float nr = sqrtf(s);
    float inv = (nr == 0.f) ? 1.f : (1.f / nr);
    int mrow = row0 + qd * 4 + rr2;
    float* orow = out + (size_t)mrow * OUT_F;
#pragma unroll
    for (int tt = 0; tt < 8; ++tt) orow[tt * 16 + r] = lv[tt][rr2] * inv;
  }
}

extern "C" void kernel_launch(void* const* d_in, const int* in_sizes, int n_in,
                              void* d_out, int out_size, void* d_ws, size_t ws_size,
                              hipStream_t stream) {
  const float* h = (const float*)d_in[0];
  const float* ppr = (const float*)d_in[1];
  const float* Qw = (const float*)d_in[2];
  const float* Qb = (const float*)d_in[3];
  const float* Ww = (const float*)d_in[4];
  const float* Wb = (const float*)d_in[5];
  const int* src = (const int*)d_in[6];
  const int* dst = (const int*)d_in[7];
  float* out = (float*)d_out;

  char* ws = (char*)d_ws;
  size_t o = 0;
  auto alloc = [&](size_t bytes) {
    void* p = ws + o;
    o = (o + bytes + 255) & ~(size_t)255;
    return p;
  };
  uint16_t* hB = (uint16_t*)alloc((size_t)N_NODES * IN_F * 2);   // 12.8 MB
  uint16_t* hqB = (uint16_t*)alloc((size_t)N_NODES * HID_F * 2); // 12.8 MB
  uint16_t* QwB = (uint16_t*)alloc((size_t)HID_F * IN_F * 2);
  uint16_t* WwB = (uint16_t*)alloc((size_t)OUT_F * CAT_F * 2);
  int* G = (int*)alloc((size_t)NBUCK * NB * 4);   // 3.2 MB
  int* Gs = (int*)alloc((size_t)NBUCK * NB * 4);  // 3.2 MB
  int* Btot = (int*)alloc((size_t)NBUCK * 4);
  int* Bbase = (int*)alloc((size_t)(NBUCK + 1) * 4);
  int2* rec = (int2*)alloc((size_t)N_EDGES * 8);  // 6.4 MB
  // total ~38.5 MB; no memset needed (all buffers fully written each call)

  const int CONV_BLOCKS = ((N_NODES * IN_F + HID_F * IN_F + OUT_F * CAT_F) / 4 + 255) / 256;
  prep_hist_kernel<<<NB + CONV_BLOCKS, 256, 0, stream>>>(dst, G, h, Qw, Ww, hB, QwB, WwB);
  bucket_scan_kernel<<<(NBUCK + 3) / 4, 256, 0, stream>>>(G, Gs, Btot);
  base_scan_kernel<<<1, 64, 0, stream>>>(Btot, Bbase);
  scatter_gemm1_kernel<<<NB + 782, 256, 0, stream>>>(dst, src, ppr, Gs, Bbase, rec, hB, QwB,
                                                     Qb, hqB);
  agg_gemm2_kernel<<<NBUCK, 256, 0, stream>>>(hqB, rec, Bbase, hB, WwB, Wb, out);
}

// Round 3
// 180.790 us; speedup vs baseline: 1.1364x; 1.1364x over previous
//
#include <hip/hip_runtime.h>
#include <stdint.h>

#define N_NODES 50000
#define N_EDGES 800000
#define IN_F 128
#define HID_F 128
#define OUT_F 128
#define CAT_F 256
#define N_STRIPS 3125  // 50000 / 16 rows per wave-strip

#define NB 256            // edge partition blocks
#define CHUNK 3136        // edges per partition (int4-aligned; 256*3136 >= 800000)
#define NBUCK 3125        // 16-node buckets (50000/16 exact)
#define BCAP 384          // per-bucket record capacity (mean 256, sigma 16, +8 sigma)

typedef __bf16 bf16x8 __attribute__((ext_vector_type(8)));
typedef float f32x4 __attribute__((ext_vector_type(4)));

__device__ __forceinline__ uint32_t f2b(float f) {
  uint32_t u = __float_as_uint(f);
  return (u + 0x7fffu + ((u >> 16) & 1u)) >> 16;  // RNE
}

// ---- K1: fused  [0,NB): per-partition bucket histogram | [NB,..): h/Qw/Ww -> bf16
__global__ void __launch_bounds__(256) prep_hist_kernel(
    const int* __restrict__ dst, int* __restrict__ G, const float* __restrict__ h,
    const float* __restrict__ Qw, const float* __restrict__ Ww, uint16_t* __restrict__ hB,
    uint16_t* __restrict__ QwB, uint16_t* __restrict__ WwB) {
  if (blockIdx.x < NB) {
    __shared__ int hist[NBUCK];  // 12.5 KB
    for (int k = threadIdx.x; k < NBUCK; k += 256) hist[k] = 0;
    __syncthreads();
    int b = blockIdx.x;
    int base = b * CHUNK;
    int end = (base + CHUNK < N_EDGES) ? (base + CHUNK) : N_EDGES;
    for (int i4 = base / 4 + threadIdx.x; i4 * 4 < end; i4 += 256) {
      int4 d4 = ((const int4*)dst)[i4];  // CHUNK,N_EDGES divisible by 4
      atomicAdd(&hist[d4.x >> 4], 1);
      atomicAdd(&hist[d4.y >> 4], 1);
      atomicAdd(&hist[d4.z >> 4], 1);
      atomicAdd(&hist[d4.w >> 4], 1);
    }
    __syncthreads();
    for (int k = threadIdx.x; k < NBUCK; k += 256) G[k * NB + b] = hist[k];
  } else {
    const int TOT4 = (N_NODES * IN_F + HID_F * IN_F + OUT_F * CAT_F) / 4;  // 1612288
    int i4 = (blockIdx.x - NB) * 256 + threadIdx.x;
    if (i4 >= TOT4) return;
    int base = i4 * 4;
    const float* src;
    uint16_t* dstp;
    int off;
    if (base < N_NODES * IN_F) {
      src = h; dstp = hB; off = base;
    } else if (base < N_NODES * IN_F + HID_F * IN_F) {
      src = Qw; dstp = QwB; off = base - N_NODES * IN_F;
    } else {
      src = Ww; dstp = WwB; off = base - N_NODES * IN_F - HID_F * IN_F;
    }
    float4 v = *(const float4*)(src + off);
    ushort4 o;
    o.x = (uint16_t)f2b(v.x); o.y = (uint16_t)f2b(v.y);
    o.z = (uint16_t)f2b(v.z); o.w = (uint16_t)f2b(v.w);
    *(ushort4*)(dstp + off) = o;
  }
}

// ---- K2a: per-bucket exclusive scan over its NB=256 partition counts (one wave/bucket)
__global__ void __launch_bounds__(256) bucket_scan_kernel(const int* __restrict__ G,
                                                          int* __restrict__ Gs,
                                                          int* __restrict__ Btot) {
  int w = (blockIdx.x * 256 + (int)threadIdx.x) >> 6;  // bucket id
  if (w >= NBUCK) return;
  int lane = threadIdx.x & 63;
  int4 v = *(const int4*)(G + (size_t)w * NB + lane * 4);
  int s = v.x + v.y + v.z + v.w;
  int inc = s;
#pragma unroll
  for (int d = 1; d < 64; d <<= 1) {
    int x = __shfl_up(inc, d, 64);
    if (lane >= d) inc += x;
  }
  int exc = inc - s;
  int4 o;
  o.x = exc;
  o.y = exc + v.x;
  o.z = exc + v.x + v.y;
  o.w = exc + v.x + v.y + v.z;
  *(int4*)(Gs + (size_t)w * NB + lane * 4) = o;
  if (lane == 63) Btot[w] = inc;
}

// ---- K2b: single-wave exclusive scan of NBUCK bucket totals -> Bbase[NBUCK+1]
__global__ void base_scan_kernel(const int* __restrict__ Btot, int* __restrict__ Bbase) {
  int lane = threadIdx.x;  // 64 threads, 49 elems each (3136 >= 3126)
  int c[49], loc[49];
  int s = 0;
#pragma unroll
  for (int j = 0; j < 49; ++j) {
    int i = lane * 49 + j;
    c[j] = (i < NBUCK) ? Btot[i] : 0;
    loc[j] = s;
    s += c[j];
  }
  int inc = s;
#pragma unroll
  for (int d = 1; d < 64; d <<= 1) {
    int x = __shfl_up(inc, d, 64);
    if (lane >= d) inc += x;
  }
  int exc = inc - s;
#pragma unroll
  for (int j = 0; j < 49; ++j) {
    int i = lane * 49 + j;
    if (i <= NBUCK) Bbase[i] = exc + loc[j];
  }
}

// ---- GEMM1 body: hq = bf16(hB @ Qw^T + Qb), one wave per 16-row strip
__device__ __forceinline__ void gemm1_body(int gb, const uint16_t* __restrict__ hB,
                                           const uint16_t* __restrict__ QwB,
                                           const float* __restrict__ Qb,
                                           uint16_t* __restrict__ hqB) {
  int wave = (gb * 256 + (int)threadIdx.x) >> 6;
  if (wave >= N_STRIPS) return;
  int lane = threadIdx.x & 63;
  int r = lane & 15, qd = lane >> 4;
  int row0 = wave * 16;
  f32x4 acc[8];
#pragma unroll
  for (int t = 0; t < 8; ++t) acc[t] = (f32x4){0.f, 0.f, 0.f, 0.f};
  const uint16_t* aRow = hB + (size_t)(row0 + r) * IN_F + qd * 8;
#pragma unroll
  for (int kt = 0; kt < 4; ++kt) {
    bf16x8 a = *(const bf16x8*)(aRow + kt * 32);
#pragma unroll
    for (int t = 0; t < 8; ++t) {
      bf16x8 b = *(const bf16x8*)(QwB + (t * 16 + r) * IN_F + kt * 32 + qd * 8);
      acc[t] = __builtin_amdgcn_mfma_f32_16x16x32_bf16(a, b, acc[t], 0, 0, 0);
    }
  }
#pragma unroll
  for (int t = 0; t < 8; ++t) {
    float qb = Qb[t * 16 + r];
#pragma unroll
    for (int rr = 0; rr < 4; ++rr) {
      int m = row0 + qd * 4 + rr;
      hqB[(size_t)m * HID_F + t * 16 + r] = (uint16_t)f2b(acc[t][rr] + qb);
    }
  }
}

// ---- K3: fused  [0,NB): LDS-cursor scatter (int4 edge loads) | [NB,..): gemm1
__global__ void __launch_bounds__(256) scatter_gemm1_kernel(
    const int* __restrict__ dst, const int* __restrict__ src, const float* __restrict__ ppr,
    const int* __restrict__ Gs, const int* __restrict__ Bbase, int2* __restrict__ rec,
    const uint16_t* __restrict__ hB, const uint16_t* __restrict__ QwB,
    const float* __restrict__ Qb, uint16_t* __restrict__ hqB) {
  if (blockIdx.x < NB) {
    __shared__ int cursor[NBUCK];  // 12.5 KB
    int b = blockIdx.x;
    for (int k = threadIdx.x; k < NBUCK; k += 256)
      cursor[k] = Bbase[k] + Gs[(size_t)k * NB + b];
    __syncthreads();
    int base = b * CHUNK;
    int end = (base + CHUNK < N_EDGES) ? (base + CHUNK) : N_EDGES;
    for (int i4 = base / 4 + threadIdx.x; i4 * 4 < end; i4 += 256) {
      int4 d4 = ((const int4*)dst)[i4];
      int4 s4 = ((const int4*)src)[i4];
      float4 w4 = ((const float4*)ppr)[i4];
      int p;
      p = atomicAdd(&cursor[d4.x >> 4], 1);
      rec[p] = make_int2(s4.x | ((d4.x & 15) << 20), __float_as_int(w4.x));
      p = atomicAdd(&cursor[d4.y >> 4], 1);
      rec[p] = make_int2(s4.y | ((d4.y & 15) << 20), __float_as_int(w4.y));
      p = atomicAdd(&cursor[d4.z >> 4], 1);
      rec[p] = make_int2(s4.z | ((d4.z & 15) << 20), __float_as_int(w4.z));
      p = atomicAdd(&cursor[d4.w >> 4], 1);
      rec[p] = make_int2(s4.w | ((d4.w & 15) << 20), __float_as_int(w4.w));
    }
  } else {
    gemm1_body(blockIdx.x - NB, hB, QwB, Qb, hqB);
  }
}

// ---- K4: fused aggregation + GEMM2. Block g (256 thr, 4 waves) owns 16 nodes.
// R3: keep R2's TLP (3125 blocks, 16-node buckets, refill) but remove the spill
// (R2's (256,8) forced VGPR=32 -> ~53 MB scratch writes/dispatch) and add
// compiler-robust ILP: 2-deep ping-pong prefetch in P4 (uA/uB statically
// indexed; sinking the prefetch would require moving loads across a full
// 160-cycle FMA block, unlike the flat u[8] batch R1 showed gets serialized).
// Target ~80 VGPR -> 6 blocks/CU resident, 8 rows in flight per wave.
__global__ void __launch_bounds__(256) agg_gemm2_kernel(
    const uint16_t* __restrict__ hqB, const int2* __restrict__ rec,
    const int* __restrict__ Bbase, const uint16_t* __restrict__ hB,
    const uint16_t* __restrict__ WwB, const float* __restrict__ Wb,
    float* __restrict__ out) {
  __shared__ int2 srec[BCAP];     // 3.0 KB
  __shared__ uint4 hagg[16][17];  // 4.4 KB (pad 16->17 breaks stride conflicts)
  __shared__ int hist[16];
  __shared__ int noff[17];
  __shared__ int cur[16];
  int g = blockIdx.x;
  int t = threadIdx.x;
  if (t < 16) hist[t] = 0;
  __syncthreads();

  int rbeg = Bbase[g];
  int len = Bbase[g + 1] - rbeg;
  len = (len < BCAP) ? len : BCAP;

  // P1: load to registers + histogram (2*256 >= BCAP)
  int2 rc[2];
#pragma unroll
  for (int k = 0; k < 2; ++k) {
    int i = t + k * 256;
    if (i < len) {
      rc[k] = rec[rbeg + i];
      atomicAdd(&hist[rc[k].x >> 20], 1);
    }
  }
  __syncthreads();

  // P2: exclusive scan of 16 counters (lanes 0..15 of wave 0)
  if (t < 16) {
    int v = hist[t];
    int inc = v;
#pragma unroll
    for (int d = 1; d < 16; d <<= 1) {
      int x = __shfl_up(inc, d, 64);
      if (t >= d) inc += x;
    }
    noff[t] = inc - v;
    cur[t] = inc - v;
    if (t == 15) noff[16] = inc;
  }
  __syncthreads();

  // P3: scatter registers -> node-sorted LDS
#pragma unroll
  for (int k = 0; k < 2; ++k) {
    int i = t + k * 256;
    if (i < len) {
      int p = atomicAdd(&cur[rc[k].x >> 20], 1);
      srec[p] = rc[k];
    }
  }
  __syncthreads();

  // P4: sub-as-node aggregation with 2-deep ping-pong prefetch.
  // 16 subs of 16 lanes; each sub owns 1 node (3125*16 = 50000 exactly).
  {
    int gs = t >> 4, c = t & 15;
    const uint4* hq4 = (const uint4*)hqB;
    int nl = gs;
    int nbeg = noff[nl], nend = noff[nl + 1];
    int last = nend - 1;
    float a[8];
#pragma unroll
    for (int j = 0; j < 8; ++j) a[j] = 0.f;
    float ws = 0.f;

    int2 rrA[4], rrB[4];
    uint4 uA[4], uB[4];

#define LOADB(E0, RR, UU)                                         \
  {                                                               \
    _Pragma("unroll") for (int j = 0; j < 4; ++j) {               \
      int i = (E0) + j;                                           \
      RR[j] = srec[(i < last) ? i : last];                        \
    }                                                             \
    _Pragma("unroll") for (int j = 0; j < 4; ++j)                 \
        UU[j] = hq4[(size_t)(RR[j].x & 0xFFFFF) * 16 + c];        \
  }

#define CONSB(E0, RR, UU)                                           \
  {                                                                 \
    _Pragma("unroll") for (int j = 0; j < 4; ++j) {                 \
      float w = ((E0) + j < nend) ? __int_as_float(RR[j].y) : 0.f;  \
      ws += w;                                                      \
      uint32_t x;                                                   \
      x = UU[j].x;                                                  \
      a[0] += w * __uint_as_float(x << 16);                         \
      a[1] += w * __uint_as_float(x & 0xffff0000u);                 \
      x = UU[j].y;                                                  \
      a[2] += w * __uint_as_float(x << 16);                         \
      a[3] += w * __uint_as_float(x & 0xffff0000u);                 \
      x = UU[j].z;                                                  \
      a[4] += w * __uint_as_float(x << 16);                         \
      a[5] += w * __uint_as_float(x & 0xffff0000u);                 \
      x = UU[j].w;                                                  \
      a[6] += w * __uint_as_float(x << 16);                         \
      a[7] += w * __uint_as_float(x & 0xffff0000u);                 \
    }                                                               \
  }

    int e = nbeg;
    if (e < nend) {
      LOADB(e, rrA, uA);
      while (true) {
        int eB = e + 4;
        if (eB < nend) {
          LOADB(eB, rrB, uB);   // B in flight while A consumed
          CONSB(e, rrA, uA);
          int eA = eB + 4;
          if (eA < nend) {
            LOADB(eA, rrA, uA); // A in flight while B consumed
            CONSB(eB, rrB, uB);
            e = eA;
          } else {
            CONSB(eB, rrB, uB);
            break;
          }
        } else {
          CONSB(e, rrA, uA);
          break;
        }
      }
    }
#undef LOADB
#undef CONSB

    float dnm = (ws == 0.f) ? 1.f : ws;  // safediv
    float inv = 1.f / dnm;
    uint4 o;
    o.x = f2b(a[0] * inv) | (f2b(a[1] * inv) << 16);
    o.y = f2b(a[2] * inv) | (f2b(a[3] * inv) << 16);
    o.z = f2b(a[4] * inv) | (f2b(a[5] * inv) << 16);
    o.w = f2b(a[6] * inv) | (f2b(a[7] * inv) << 16);
    hagg[nl][c] = o;
  }
  __syncthreads();

  // P5: gemm2 on wave 0 (16-row strip); waves 1-3 retire
  int lane = t & 63, wv = t >> 6;
  if (wv != 0) return;
  int row0 = g * 16;
  int r = lane & 15, qd = lane >> 4;
  f32x4 acc[8];
#pragma unroll
  for (int tt = 0; tt < 8; ++tt) acc[tt] = (f32x4){0.f, 0.f, 0.f, 0.f};
  const uint16_t* aRow = hB + (size_t)(row0 + r) * IN_F + qd * 8;
#pragma unroll
  for (int kt = 0; kt < 8; ++kt) {
    bf16x8 av;
    if (kt < 4) {
      av = *(const bf16x8*)(aRow + kt * 32);
    } else {
      av = *(const bf16x8*)&hagg[r][(kt - 4) * 4 + qd];
    }
#pragma unroll
    for (int tt = 0; tt < 8; ++tt) {
      bf16x8 b = *(const bf16x8*)(WwB + (tt * 16 + r) * CAT_F + kt * 32 + qd * 8);
      acc[tt] = __builtin_amdgcn_mfma_f32_16x16x32_bf16(av, b, acc[tt], 0, 0, 0);
    }
  }
  float lv[8][4];
  float ss[4] = {0.f, 0.f, 0.f, 0.f};
#pragma unroll
  for (int tt = 0; tt < 8; ++tt) {
    float wb = Wb[tt * 16 + r];
#pragma unroll
    for (int rr2 = 0; rr2 < 4; ++rr2) {
      float v = acc[tt][rr2] + wb;
      v = (v >= 0.f) ? v : 0.01f * v;
      lv[tt][rr2] = v;
      ss[rr2] += v * v;
    }
  }
#pragma unroll
  for (int rr2 = 0; rr2 < 4; ++rr2) {
    float s = ss[rr2];
    s += __shfl_xor(s, 1);
    s += __shfl_xor(s, 2);
    s += __shfl_xor(s, 4);
    s += __shfl_xor(s, 8);
    float nr = sqrtf(s);
    float inv = (nr == 0.f) ? 1.f : (1.f / nr);
    int mrow = row0 + qd * 4 + rr2;
    float* orow = out + (size_t)mrow * OUT_F;
#pragma unroll
    for (int tt = 0; tt < 8; ++tt) orow[tt * 16 + r] = lv[tt][rr2] * inv;
  }
}

extern "C" void kernel_launch(void* const* d_in, const int* in_sizes, int n_in,
                              void* d_out, int out_size, void* d_ws, size_t ws_size,
                              hipStream_t stream) {
  const float* h = (const float*)d_in[0];
  const float* ppr = (const float*)d_in[1];
  const float* Qw = (const float*)d_in[2];
  const float* Qb = (const float*)d_in[3];
  const float* Ww = (const float*)d_in[4];
  const float* Wb = (const float*)d_in[5];
  const int* src = (const int*)d_in[6];
  const int* dst = (const int*)d_in[7];
  float* out = (float*)d_out;

  char* ws = (char*)d_ws;
  size_t o = 0;
  auto alloc = [&](size_t bytes) {
    void* p = ws + o;
    o = (o + bytes + 255) & ~(size_t)255;
    return p;
  };
  uint16_t* hB = (uint16_t*)alloc((size_t)N_NODES * IN_F * 2);   // 12.8 MB
  uint16_t* hqB = (uint16_t*)alloc((size_t)N_NODES * HID_F * 2); // 12.8 MB
  uint16_t* QwB = (uint16_t*)alloc((size_t)HID_F * IN_F * 2);
  uint16_t* WwB = (uint16_t*)alloc((size_t)OUT_F * CAT_F * 2);
  int* G = (int*)alloc((size_t)NBUCK * NB * 4);   // 3.2 MB
  int* Gs = (int*)alloc((size_t)NBUCK * NB * 4);  // 3.2 MB
  int* Btot = (int*)alloc((size_t)NBUCK * 4);
  int* Bbase = (int*)alloc((size_t)(NBUCK + 1) * 4);
  int2* rec = (int2*)alloc((size_t)N_EDGES * 8);  // 6.4 MB
  // total ~38.5 MB; no memset needed (all buffers fully written each call)

  const int CONV_BLOCKS = ((N_NODES * IN_F + HID_F * IN_F + OUT_F * CAT_F) / 4 + 255) / 256;
  prep_hist_kernel<<<NB + CONV_BLOCKS, 256, 0, stream>>>(dst, G, h, Qw, Ww, hB, QwB, WwB);
  bucket_scan_kernel<<<(NBUCK + 3) / 4, 256, 0, stream>>>(G, Gs, Btot);
  base_scan_kernel<<<1, 64, 0, stream>>>(Btot, Bbase);
  scatter_gemm1_kernel<<<NB + 782, 256, 0, stream>>>(dst, src, ppr, Gs, Bbase, rec, hB, QwB,
                                                     Qb, hqB);
  agg_gemm2_kernel<<<NBUCK, 256, 0, stream>>>(hqB, rec, Bbase, hB, WwB, Wb, out);
}